// Round 1
// baseline (1041.005 us; speedup 1.0000x reference)
//
#include <hip/hip_runtime.h>
#include <hip/hip_bf16.h>

#define N_NODES 38332
#define POI_LEN 38333
#define CAT_LEN 400
#define POI_DIM 300
#define CAT_DIM 100
#define GCN_CH 64
#define N_EDGES (N_NODES * 32)
#define NEG_SLOPE 0.01f

// ---------------- CSR build ----------------

__global__ void k_zero(int* __restrict__ cnt, float* __restrict__ h128) {
  int i = blockIdx.x * 256 + threadIdx.x;
  if (i < N_NODES) cnt[i] = 0;
  if (i < 128) h128[i] = 0.f;
}

__global__ void k_count(const int* __restrict__ dst, int* __restrict__ cnt) {
  int e = blockIdx.x * 256 + threadIdx.x;
  if (e < N_EDGES) atomicAdd(&cnt[dst[e]], 1);
}

// single-block exclusive scan over counts; also writes cursor copy, deg^-1/2
__global__ __launch_bounds__(1024) void k_scan(const int* __restrict__ cnt,
                                               int* __restrict__ row_start,
                                               int* __restrict__ cursor,
                                               float* __restrict__ dinv) {
  __shared__ int sb[1024];
  __shared__ int s_tot;
  int tid = threadIdx.x;
  int running = 0;
  for (int base = 0; base < N_NODES; base += 1024) {
    int i = base + tid;
    int v = (i < N_NODES) ? cnt[i] : 0;
    sb[tid] = v;
    __syncthreads();
    for (int off = 1; off < 1024; off <<= 1) {
      int t = (tid >= off) ? sb[tid - off] : 0;
      __syncthreads();
      if (tid >= off) sb[tid] += t;
      __syncthreads();
    }
    int incl = sb[tid];
    if (i < N_NODES) {
      int rs = running + incl - v;
      row_start[i] = rs;
      cursor[i] = rs;
      dinv[i] = 1.0f / sqrtf((float)(v + 1));  // deg includes self loop
    }
    if (tid == 1023) s_tot = incl;
    __syncthreads();
    running += s_tot;
  }
  if (tid == 0) row_start[N_NODES] = running;
}

__global__ void k_scatter(const int* __restrict__ src, const int* __restrict__ dst,
                          int* __restrict__ cursor, int* __restrict__ csr_src) {
  int e = blockIdx.x * 256 + threadIdx.x;
  if (e < N_EDGES) {
    int d = dst[e];
    int pos = atomicAdd(&cursor[d], 1);
    csr_src[pos] = src[e];
  }
}

// ---------------- input transform: hs = (gathered_feat @ W_in) * dinv --------

__global__ __launch_bounds__(256) void k_in_xform(
    const float* __restrict__ x, const float* __restrict__ poi_emb,
    const float* __restrict__ cat_emb, const float* __restrict__ W_in,
    const float* __restrict__ dinv, float* __restrict__ hs) {
  __shared__ float sfeat[4][404];
  int lane = threadIdx.x & 63;
  int w = threadIdx.x >> 6;
  int node = blockIdx.x * 4 + w;  // N_NODES % 4 == 0

  int pid = (int)x[node * 5 + 0];
  int cid = (int)x[node * 5 + 1];
  const float* pe = poi_emb + (size_t)pid * POI_DIM;
  for (int k = lane; k < POI_DIM; k += 64) sfeat[w][k] = pe[k];
  const float* ce = cat_emb + (size_t)cid * CAT_DIM;
  for (int k = lane; k < CAT_DIM; k += 64) sfeat[w][POI_DIM + k] = ce[k];
  if (lane < 3) sfeat[w][400 + lane] = x[node * 5 + 2 + lane];
  __syncthreads();

  float acc = 0.f;
  const float4* sf4 = (const float4*)&sfeat[w][0];
  for (int k4 = 0; k4 < 100; k4++) {
    float4 f4 = sf4[k4];
    int k = k4 * 4;
    acc += f4.x * W_in[(k + 0) * 64 + lane];
    acc += f4.y * W_in[(k + 1) * 64 + lane];
    acc += f4.z * W_in[(k + 2) * 64 + lane];
    acc += f4.w * W_in[(k + 3) * 64 + lane];
  }
  for (int k = 400; k < 403; k++) acc += sfeat[w][k] * W_in[k * 64 + lane];
  hs[(size_t)node * 64 + lane] = acc * dinv[node];
}

// ---------------- middle transform: hs = (feat @ W) * dinv ----------------

__global__ __launch_bounds__(256) void k_xform(const float* __restrict__ feat,
                                               const float* __restrict__ W,
                                               const float* __restrict__ dinv,
                                               float* __restrict__ hs) {
  __shared__ float sW[64 * 64];
  int tid = threadIdx.x;
  int lane = tid & 63;
  int w = tid >> 6;
  for (int k = tid; k < 64 * 64; k += 256) sW[k] = W[k];
  __syncthreads();
  int node = blockIdx.x * 4 + w;
  float f = feat[(size_t)node * 64 + lane];
  float acc = 0.f;
#pragma unroll
  for (int k = 0; k < 64; k++) {
    float fk = __shfl(f, k, 64);
    acc += fk * sW[k * 64 + lane];
  }
  hs[(size_t)node * 64 + lane] = acc * dinv[node];
}

// ---------------- aggregation + epilogue ----------------
// t = dinv[i]*(sum_edges hs[src] + hs[i]) + b;  MODE 0: leaky(t)   MODE 1: leaky(t)+t

template <int MODE>
__global__ __launch_bounds__(256) void k_agg(const float* __restrict__ hs,
                                             const int* __restrict__ row_start,
                                             const int* __restrict__ csr_src,
                                             const float* __restrict__ dinv,
                                             const float* __restrict__ bias,
                                             float* __restrict__ out) {
  int lane = threadIdx.x & 63;
  int w = threadIdx.x >> 6;
  int node = blockIdx.x * 4 + w;
  int r0 = row_start[node];
  int r1 = row_start[node + 1];
  float acc = 0.f;
#pragma unroll 4
  for (int e = r0; e < r1; e++) {
    int s = csr_src[e];  // wave-uniform broadcast load (L1-hit, sequential)
    acc += hs[(size_t)s * 64 + lane];
  }
  float t = dinv[node] * (acc + hs[(size_t)node * 64 + lane]) + bias[lane];
  float lt = (t >= 0.f) ? t : NEG_SLOPE * t;
  out[(size_t)node * 64 + lane] = MODE ? (lt + t) : lt;
}

// ---------------- output head (64 -> 1) ----------------

__global__ __launch_bounds__(256) void k_out_xform(const float* __restrict__ feat,
                                                   const float* __restrict__ W_out,
                                                   const float* __restrict__ dinv,
                                                   float* __restrict__ hs1) {
  int lane = threadIdx.x & 63;
  int w = threadIdx.x >> 6;
  int node = blockIdx.x * 4 + w;
  float v = feat[(size_t)node * 64 + lane] * W_out[lane];
#pragma unroll
  for (int off = 32; off; off >>= 1) v += __shfl_xor(v, off, 64);
  if (lane == 0) hs1[node] = v * dinv[node];
}

__global__ __launch_bounds__(256) void k_out_agg(const float* __restrict__ hs1,
                                                 const int* __restrict__ row_start,
                                                 const int* __restrict__ csr_src,
                                                 const float* __restrict__ dinv,
                                                 const float* __restrict__ b_out,
                                                 float* __restrict__ g) {
  int lane = threadIdx.x & 63;
  int w = threadIdx.x >> 6;
  int node = blockIdx.x * 4 + w;
  int r0 = row_start[node];
  int r1 = row_start[node + 1];
  float acc = 0.f;
  for (int e = r0 + lane; e < r1; e += 64) acc += hs1[csr_src[e]];
#pragma unroll
  for (int off = 32; off; off >>= 1) acc += __shfl_xor(acc, off, 64);
  if (lane == 0) {
    float t = dinv[node] * (acc + hs1[node]) + b_out[0];
    g[node] = (t >= 0.f) ? t : NEG_SLOPE * t;
  }
}

// ---------------- FC head ----------------

__global__ __launch_bounds__(128) void k_fc1(const float* __restrict__ g,
                                             const float* __restrict__ fc1_W,
                                             float* __restrict__ h128) {
  int j = threadIdx.x;  // 0..127
  int base = blockIdx.x * 128;
  int end = base + 128;
  if (end > N_NODES) end = N_NODES;
  float acc = 0.f;
  for (int i = base; i < end; i++) acc += g[i] * fc1_W[(size_t)i * 128 + j];
  atomicAdd(&h128[j], acc);
}

__global__ __launch_bounds__(256) void k_fc2(const float* __restrict__ h128raw,
                                             const float* __restrict__ fc1_b,
                                             const float* __restrict__ fc2_W,
                                             const float* __restrict__ fc2_b,
                                             float* __restrict__ out) {
  __shared__ float sh[128];
  int tid = threadIdx.x;
  if (tid < 128) {
    float v = h128raw[tid] + fc1_b[tid];
    sh[tid] = (v > 0.f) ? v : 0.f;
  }
  __syncthreads();
  int p = blockIdx.x * 256 + tid;
  if (p < POI_LEN) {
    float acc = fc2_b[p];
#pragma unroll 8
    for (int j = 0; j < 128; j++) acc += sh[j] * fc2_W[(size_t)j * POI_LEN + p];
    out[p] = (acc > 0.f) ? acc : 0.f;
  }
}

// ---------------- launch ----------------

extern "C" void kernel_launch(void* const* d_in, const int* in_sizes, int n_in,
                              void* d_out, int out_size, void* d_ws, size_t ws_size,
                              hipStream_t stream) {
  const float* x       = (const float*)d_in[0];
  const int*   ei      = (const int*)d_in[1];
  const float* poi_emb = (const float*)d_in[2];
  const float* cat_emb = (const float*)d_in[3];
  const float* W_in    = (const float*)d_in[4];
  const float* b_in    = (const float*)d_in[5];
  const float* gcn_Ws  = (const float*)d_in[6];
  const float* gcn_bs  = (const float*)d_in[7];
  const float* W_out   = (const float*)d_in[8];
  const float* b_out   = (const float*)d_in[9];
  const float* fc1_W   = (const float*)d_in[10];
  const float* fc1_b   = (const float*)d_in[11];
  const float* fc2_W   = (const float*)d_in[12];
  const float* fc2_b   = (const float*)d_in[13];
  const int* src = ei;
  const int* dst = ei + N_EDGES;

  char* p = (char*)d_ws;
  auto take = [&](size_t bytes) {
    char* r = p;
    p += (bytes + 255) & ~(size_t)255;
    return r;
  };
  int*   cnt       = (int*)take((size_t)N_NODES * 4);
  int*   cursor    = (int*)take((size_t)N_NODES * 4);
  int*   row_start = (int*)take((size_t)(N_NODES + 1) * 4);
  float* dinv      = (float*)take((size_t)N_NODES * 4);
  int*   csr_src   = (int*)take((size_t)N_EDGES * 4);
  float* feat      = (float*)take((size_t)N_NODES * 64 * 4);
  float* hs        = (float*)take((size_t)N_NODES * 64 * 4);
  float* hs1       = (float*)take((size_t)N_NODES * 4);
  float* g         = (float*)take((size_t)N_NODES * 4);
  float* h128      = (float*)take(128 * 4);
  float* out       = (float*)d_out;

  const int nb4 = N_NODES / 4;                // 9583 blocks, 4 nodes each
  const int nbE = (N_EDGES + 255) / 256;      // 4792

  k_zero<<<(N_NODES + 255) / 256, 256, 0, stream>>>(cnt, h128);
  k_count<<<nbE, 256, 0, stream>>>(dst, cnt);
  k_scan<<<1, 1024, 0, stream>>>(cnt, row_start, cursor, dinv);
  k_scatter<<<nbE, 256, 0, stream>>>(src, dst, cursor, csr_src);

  k_in_xform<<<nb4, 256, 0, stream>>>(x, poi_emb, cat_emb, W_in, dinv, hs);
  k_agg<0><<<nb4, 256, 0, stream>>>(hs, row_start, csr_src, dinv, b_in, feat);

  for (int l = 0; l < 5; l++) {
    k_xform<<<nb4, 256, 0, stream>>>(feat, gcn_Ws + (size_t)l * 64 * 64, dinv, hs);
    k_agg<1><<<nb4, 256, 0, stream>>>(hs, row_start, csr_src, dinv, gcn_bs + (size_t)l * 64, feat);
  }

  k_out_xform<<<nb4, 256, 0, stream>>>(feat, W_out, dinv, hs1);
  k_out_agg<<<nb4, 256, 0, stream>>>(hs1, row_start, csr_src, dinv, b_out, g);
  k_fc1<<<(N_NODES + 127) / 128, 128, 0, stream>>>(g, fc1_W, h128);
  k_fc2<<<(POI_LEN + 255) / 256, 256, 0, stream>>>(h128, fc1_b, fc2_W, fc2_b, out);
}

// Round 2
// 949.266 us; speedup vs baseline: 1.0966x; 1.0966x over previous
//
#include <hip/hip_runtime.h>
#include <hip/hip_bf16.h>

#define N_NODES 38332
#define POI_LEN 38333
#define CAT_LEN 400
#define POI_DIM 300
#define CAT_DIM 100
#define GCN_CH 64
#define N_EDGES (N_NODES * 32)
#define NEG_SLOPE 0.01f
#define TILE_N 32
#define N_CHUNKS ((N_NODES + 255) / 256)  // 150

// ---------------- CSR build ----------------

__global__ void k_zero(int* __restrict__ cnt, float* __restrict__ h128) {
  int i = blockIdx.x * 256 + threadIdx.x;
  if (i < N_NODES) cnt[i] = 0;
  if (i < 128) h128[i] = 0.f;
}

__global__ void k_count(const int* __restrict__ dst, int* __restrict__ cnt) {
  int e = blockIdx.x * 256 + threadIdx.x;
  if (e < N_EDGES) atomicAdd(&cnt[dst[e]], 1);
}

// phase 1: per-chunk sums (+ dinv, which only needs cnt)
__global__ __launch_bounds__(256) void k_scan1(const int* __restrict__ cnt,
                                               int* __restrict__ partial,
                                               float* __restrict__ dinv) {
  __shared__ int sb[256];
  int tid = threadIdx.x;
  int i = blockIdx.x * 256 + tid;
  int v = (i < N_NODES) ? cnt[i] : 0;
  if (i < N_NODES) dinv[i] = 1.0f / sqrtf((float)(v + 1));  // deg incl self loop
  sb[tid] = v;
  __syncthreads();
  for (int off = 128; off; off >>= 1) {
    if (tid < off) sb[tid] += sb[tid + off];
    __syncthreads();
  }
  if (tid == 0) partial[blockIdx.x] = sb[0];
}

// phase 2: single-block exclusive scan of the 150 partials
__global__ __launch_bounds__(256) void k_scan2(int* __restrict__ partial) {
  __shared__ int sb[256];
  int tid = threadIdx.x;
  int v = (tid < N_CHUNKS) ? partial[tid] : 0;
  sb[tid] = v;
  __syncthreads();
  for (int off = 1; off < 256; off <<= 1) {
    int t = (tid >= off) ? sb[tid - off] : 0;
    __syncthreads();
    sb[tid] += t;
    __syncthreads();
  }
  if (tid < N_CHUNKS) partial[tid] = sb[tid] - v;  // exclusive
}

// phase 3: local scan + chunk offset -> row_start, cursor
__global__ __launch_bounds__(256) void k_scan3(const int* __restrict__ cnt,
                                               const int* __restrict__ partial,
                                               int* __restrict__ row_start,
                                               int* __restrict__ cursor) {
  __shared__ int sb[256];
  int tid = threadIdx.x;
  int i = blockIdx.x * 256 + tid;
  int v = (i < N_NODES) ? cnt[i] : 0;
  sb[tid] = v;
  __syncthreads();
  for (int off = 1; off < 256; off <<= 1) {
    int t = (tid >= off) ? sb[tid - off] : 0;
    __syncthreads();
    sb[tid] += t;
    __syncthreads();
  }
  if (i < N_NODES) {
    int rs = partial[blockIdx.x] + sb[tid] - v;
    row_start[i] = rs;
    cursor[i] = rs;
  }
  if (i == N_NODES - 1) row_start[N_NODES] = partial[blockIdx.x] + sb[tid];
}

__global__ void k_scatter(const int* __restrict__ src, const int* __restrict__ dst,
                          int* __restrict__ cursor, int* __restrict__ csr_src) {
  int e = blockIdx.x * 256 + threadIdx.x;
  if (e < N_EDGES) {
    int d = dst[e];
    int pos = atomicAdd(&cursor[d], 1);
    csr_src[pos] = src[e];
  }
}

// ---------------- input transform: hs = (gathered_feat @ W_in) * dinv --------
// 32 nodes/block; each wave computes 8 nodes so each W_in load is reused 8x in
// registers (was 1x -> ~4 GB of L2 W-traffic; now ~0.5 GB).

__global__ __launch_bounds__(256) void k_in_xform(
    const float* __restrict__ x, const float* __restrict__ poi_emb,
    const float* __restrict__ cat_emb, const float* __restrict__ W_in,
    const float* __restrict__ dinv, float* __restrict__ hs) {
  __shared__ float sfeat[TILE_N][404];  // 404 floats: 403 + pad, 16B-aligned rows
  int tid = threadIdx.x;
  int lane = tid & 63;
  int wv = tid >> 6;  // 0..3
  int node0 = blockIdx.x * TILE_N;

  // stage gathered features; wave wv stages nodes wv, wv+4, ...
  for (int n = wv; n < TILE_N; n += 4) {
    int node = node0 + n;
    if (node < N_NODES) {
      int pid = (int)x[node * 5 + 0];
      int cid = (int)x[node * 5 + 1];
      const float* pe = poi_emb + (size_t)pid * POI_DIM;
      for (int k = lane; k < POI_DIM; k += 64) sfeat[n][k] = pe[k];
      const float* ce = cat_emb + (size_t)cid * CAT_DIM;
      for (int k = lane; k < CAT_DIM; k += 64) sfeat[n][POI_DIM + k] = ce[k];
      if (lane < 3) sfeat[n][400 + lane] = x[node * 5 + 2 + lane];
      if (lane == 3) sfeat[n][403] = 0.f;
    }
  }
  __syncthreads();

  float acc[8];
#pragma unroll
  for (int n = 0; n < 8; n++) acc[n] = 0.f;
  const int nbase = wv * 8;

  for (int k4 = 0; k4 < 100; k4++) {
    int k = k4 * 4;
    float w0 = W_in[(k + 0) * 64 + lane];
    float w1 = W_in[(k + 1) * 64 + lane];
    float w2 = W_in[(k + 2) * 64 + lane];
    float w3 = W_in[(k + 3) * 64 + lane];
#pragma unroll
    for (int n = 0; n < 8; n++) {
      const float4 f4 = *(const float4*)&sfeat[nbase + n][k];
      acc[n] += f4.x * w0 + f4.y * w1 + f4.z * w2 + f4.w * w3;
    }
  }
  {  // tail rows 400..402
    float w0 = W_in[400 * 64 + lane];
    float w1 = W_in[401 * 64 + lane];
    float w2 = W_in[402 * 64 + lane];
#pragma unroll
    for (int n = 0; n < 8; n++) {
      acc[n] += sfeat[nbase + n][400] * w0 + sfeat[nbase + n][401] * w1 +
                sfeat[nbase + n][402] * w2;
    }
  }
#pragma unroll
  for (int n = 0; n < 8; n++) {
    int node = node0 + nbase + n;
    if (node < N_NODES) hs[(size_t)node * 64 + lane] = acc[n] * dinv[node];
  }
}

// ---------------- middle transform: hs = (feat @ W) * dinv ----------------

__global__ __launch_bounds__(256) void k_xform(const float* __restrict__ feat,
                                               const float* __restrict__ W,
                                               const float* __restrict__ dinv,
                                               float* __restrict__ hs) {
  __shared__ float sW[64 * 64];
  int tid = threadIdx.x;
  int lane = tid & 63;
  int w = tid >> 6;
  for (int k = tid; k < 64 * 64; k += 256) sW[k] = W[k];
  __syncthreads();
  int node = blockIdx.x * 4 + w;
  float f = feat[(size_t)node * 64 + lane];
  float acc = 0.f;
#pragma unroll
  for (int k = 0; k < 64; k++) {
    float fk = __shfl(f, k, 64);
    acc += fk * sW[k * 64 + lane];
  }
  hs[(size_t)node * 64 + lane] = acc * dinv[node];
}

// ---------------- aggregation + epilogue ----------------
// t = dinv[i]*(sum_edges hs[src] + hs[i]) + b;  MODE 0: leaky(t)  MODE 1: leaky(t)+t
// Manual 4-deep ILP: 4 independent accumulators, batched index loads.

template <int MODE>
__global__ __launch_bounds__(256) void k_agg(const float* __restrict__ hs,
                                             const int* __restrict__ row_start,
                                             const int* __restrict__ csr_src,
                                             const float* __restrict__ dinv,
                                             const float* __restrict__ bias,
                                             float* __restrict__ out) {
  int lane = threadIdx.x & 63;
  int w = threadIdx.x >> 6;
  int node = blockIdx.x * 4 + w;
  int r0 = row_start[node];
  int r1 = row_start[node + 1];
  float a0 = 0.f, a1 = 0.f, a2 = 0.f, a3 = 0.f;
  int e = r0;
  for (; e + 4 <= r1; e += 4) {
    int s0 = csr_src[e + 0];
    int s1 = csr_src[e + 1];
    int s2 = csr_src[e + 2];
    int s3 = csr_src[e + 3];
    a0 += hs[(size_t)s0 * 64 + lane];
    a1 += hs[(size_t)s1 * 64 + lane];
    a2 += hs[(size_t)s2 * 64 + lane];
    a3 += hs[(size_t)s3 * 64 + lane];
  }
  for (; e < r1; e++) a0 += hs[(size_t)csr_src[e] * 64 + lane];
  float acc = (a0 + a1) + (a2 + a3);
  float t = dinv[node] * (acc + hs[(size_t)node * 64 + lane]) + bias[lane];
  float lt = (t >= 0.f) ? t : NEG_SLOPE * t;
  out[(size_t)node * 64 + lane] = MODE ? (lt + t) : lt;
}

// ---------------- output head (64 -> 1) ----------------

__global__ __launch_bounds__(256) void k_out_xform(const float* __restrict__ feat,
                                                   const float* __restrict__ W_out,
                                                   const float* __restrict__ dinv,
                                                   float* __restrict__ hs1) {
  int lane = threadIdx.x & 63;
  int w = threadIdx.x >> 6;
  int node = blockIdx.x * 4 + w;
  float v = feat[(size_t)node * 64 + lane] * W_out[lane];
#pragma unroll
  for (int off = 32; off; off >>= 1) v += __shfl_xor(v, off, 64);
  if (lane == 0) hs1[node] = v * dinv[node];
}

__global__ __launch_bounds__(256) void k_out_agg(const float* __restrict__ hs1,
                                                 const int* __restrict__ row_start,
                                                 const int* __restrict__ csr_src,
                                                 const float* __restrict__ dinv,
                                                 const float* __restrict__ b_out,
                                                 float* __restrict__ g) {
  int lane = threadIdx.x & 63;
  int w = threadIdx.x >> 6;
  int node = blockIdx.x * 4 + w;
  int r0 = row_start[node];
  int r1 = row_start[node + 1];
  float acc = 0.f;
  for (int e = r0 + lane; e < r1; e += 64) acc += hs1[csr_src[e]];
#pragma unroll
  for (int off = 32; off; off >>= 1) acc += __shfl_xor(acc, off, 64);
  if (lane == 0) {
    float t = dinv[node] * (acc + hs1[node]) + b_out[0];
    g[node] = (t >= 0.f) ? t : NEG_SLOPE * t;
  }
}

// ---------------- FC head ----------------

__global__ __launch_bounds__(128) void k_fc1(const float* __restrict__ g,
                                             const float* __restrict__ fc1_W,
                                             float* __restrict__ h128) {
  int j = threadIdx.x;  // 0..127
  int base = blockIdx.x * 128;
  int end = base + 128;
  if (end > N_NODES) end = N_NODES;
  float acc = 0.f;
  for (int i = base; i < end; i++) acc += g[i] * fc1_W[(size_t)i * 128 + j];
  atomicAdd(&h128[j], acc);
}

__global__ __launch_bounds__(256) void k_fc2(const float* __restrict__ h128raw,
                                             const float* __restrict__ fc1_b,
                                             const float* __restrict__ fc2_W,
                                             const float* __restrict__ fc2_b,
                                             float* __restrict__ out) {
  __shared__ float sh[128];
  int tid = threadIdx.x;
  if (tid < 128) {
    float v = h128raw[tid] + fc1_b[tid];
    sh[tid] = (v > 0.f) ? v : 0.f;
  }
  __syncthreads();
  int p = blockIdx.x * 256 + tid;
  if (p < POI_LEN) {
    float acc = fc2_b[p];
#pragma unroll 8
    for (int j = 0; j < 128; j++) acc += sh[j] * fc2_W[(size_t)j * POI_LEN + p];
    out[p] = (acc > 0.f) ? acc : 0.f;
  }
}

// ---------------- launch ----------------

extern "C" void kernel_launch(void* const* d_in, const int* in_sizes, int n_in,
                              void* d_out, int out_size, void* d_ws, size_t ws_size,
                              hipStream_t stream) {
  const float* x       = (const float*)d_in[0];
  const int*   ei      = (const int*)d_in[1];
  const float* poi_emb = (const float*)d_in[2];
  const float* cat_emb = (const float*)d_in[3];
  const float* W_in    = (const float*)d_in[4];
  const float* b_in    = (const float*)d_in[5];
  const float* gcn_Ws  = (const float*)d_in[6];
  const float* gcn_bs  = (const float*)d_in[7];
  const float* W_out   = (const float*)d_in[8];
  const float* b_out   = (const float*)d_in[9];
  const float* fc1_W   = (const float*)d_in[10];
  const float* fc1_b   = (const float*)d_in[11];
  const float* fc2_W   = (const float*)d_in[12];
  const float* fc2_b   = (const float*)d_in[13];
  const int* src = ei;
  const int* dst = ei + N_EDGES;

  char* p = (char*)d_ws;
  auto take = [&](size_t bytes) {
    char* r = p;
    p += (bytes + 255) & ~(size_t)255;
    return r;
  };
  int*   cnt       = (int*)take((size_t)N_NODES * 4);
  int*   cursor    = (int*)take((size_t)N_NODES * 4);
  int*   row_start = (int*)take((size_t)(N_NODES + 1) * 4);
  float* dinv      = (float*)take((size_t)N_NODES * 4);
  int*   csr_src   = (int*)take((size_t)N_EDGES * 4);
  float* feat      = (float*)take((size_t)N_NODES * 64 * 4);
  float* hs        = (float*)take((size_t)N_NODES * 64 * 4);
  float* hs1       = (float*)take((size_t)N_NODES * 4);
  float* g         = (float*)take((size_t)N_NODES * 4);
  float* h128      = (float*)take(128 * 4);
  int*   partial   = (int*)take((size_t)N_CHUNKS * 4);
  float* out       = (float*)d_out;

  const int nb4 = N_NODES / 4;            // 9583
  const int nbE = (N_EDGES + 255) / 256;  // 4792

  k_zero<<<(N_NODES + 255) / 256, 256, 0, stream>>>(cnt, h128);
  k_count<<<nbE, 256, 0, stream>>>(dst, cnt);
  k_scan1<<<N_CHUNKS, 256, 0, stream>>>(cnt, partial, dinv);
  k_scan2<<<1, 256, 0, stream>>>(partial);
  k_scan3<<<N_CHUNKS, 256, 0, stream>>>(cnt, partial, row_start, cursor);
  k_scatter<<<nbE, 256, 0, stream>>>(src, dst, cursor, csr_src);

  k_in_xform<<<(N_NODES + TILE_N - 1) / TILE_N, 256, 0, stream>>>(
      x, poi_emb, cat_emb, W_in, dinv, hs);
  k_agg<0><<<nb4, 256, 0, stream>>>(hs, row_start, csr_src, dinv, b_in, feat);

  for (int l = 0; l < 5; l++) {
    k_xform<<<nb4, 256, 0, stream>>>(feat, gcn_Ws + (size_t)l * 64 * 64, dinv, hs);
    k_agg<1><<<nb4, 256, 0, stream>>>(hs, row_start, csr_src, dinv,
                                      gcn_bs + (size_t)l * 64, feat);
  }

  k_out_xform<<<nb4, 256, 0, stream>>>(feat, W_out, dinv, hs1);
  k_out_agg<<<nb4, 256, 0, stream>>>(hs1, row_start, csr_src, dinv, b_out, g);
  k_fc1<<<(N_NODES + 127) / 128, 128, 0, stream>>>(g, fc1_W, h128);
  k_fc2<<<(POI_LEN + 255) / 256, 256, 0, stream>>>(h128, fc1_b, fc2_W, fc2_b, out);
}

// Round 3
// 943.084 us; speedup vs baseline: 1.1038x; 1.0066x over previous
//
#include <hip/hip_runtime.h>
#include <hip/hip_bf16.h>

#define N_NODES 38332
#define POI_LEN 38333
#define CAT_LEN 400
#define POI_DIM 300
#define CAT_DIM 100
#define GCN_CH 64
#define N_EDGES (N_NODES * 32)
#define NEG_SLOPE 0.01f
#define N_CHUNKS ((N_NODES + 255) / 256)  // 150
#define PROJ_CHUNK 20

// ---------------- CSR build ----------------

__global__ void k_zero(int* __restrict__ cnt, float* __restrict__ h128) {
  int i = blockIdx.x * 256 + threadIdx.x;
  if (i < N_NODES) cnt[i] = 0;
  if (i < 128) h128[i] = 0.f;
}

__global__ void k_count(const int* __restrict__ dst, int* __restrict__ cnt) {
  int e = blockIdx.x * 256 + threadIdx.x;
  if (e < N_EDGES) atomicAdd(&cnt[dst[e]], 1);
}

// phase 1: per-chunk sums (+ dinv, which only needs cnt)
__global__ __launch_bounds__(256) void k_scan1(const int* __restrict__ cnt,
                                               int* __restrict__ partial,
                                               float* __restrict__ dinv) {
  __shared__ int sb[256];
  int tid = threadIdx.x;
  int i = blockIdx.x * 256 + tid;
  int v = (i < N_NODES) ? cnt[i] : 0;
  if (i < N_NODES) dinv[i] = 1.0f / sqrtf((float)(v + 1));  // deg incl self loop
  sb[tid] = v;
  __syncthreads();
  for (int off = 128; off; off >>= 1) {
    if (tid < off) sb[tid] += sb[tid + off];
    __syncthreads();
  }
  if (tid == 0) partial[blockIdx.x] = sb[0];
}

// phase 2: single-block exclusive scan of the 150 partials
__global__ __launch_bounds__(256) void k_scan2(int* __restrict__ partial) {
  __shared__ int sb[256];
  int tid = threadIdx.x;
  int v = (tid < N_CHUNKS) ? partial[tid] : 0;
  sb[tid] = v;
  __syncthreads();
  for (int off = 1; off < 256; off <<= 1) {
    int t = (tid >= off) ? sb[tid - off] : 0;
    __syncthreads();
    sb[tid] += t;
    __syncthreads();
  }
  if (tid < N_CHUNKS) partial[tid] = sb[tid] - v;  // exclusive
}

// phase 3: local scan + chunk offset -> row_start, cursor
__global__ __launch_bounds__(256) void k_scan3(const int* __restrict__ cnt,
                                               const int* __restrict__ partial,
                                               int* __restrict__ row_start,
                                               int* __restrict__ cursor) {
  __shared__ int sb[256];
  int tid = threadIdx.x;
  int i = blockIdx.x * 256 + tid;
  int v = (i < N_NODES) ? cnt[i] : 0;
  sb[tid] = v;
  __syncthreads();
  for (int off = 1; off < 256; off <<= 1) {
    int t = (tid >= off) ? sb[tid - off] : 0;
    __syncthreads();
    sb[tid] += t;
    __syncthreads();
  }
  if (i < N_NODES) {
    int rs = partial[blockIdx.x] + sb[tid] - v;
    row_start[i] = rs;
    cursor[i] = rs;
  }
  if (i == N_NODES - 1) row_start[N_NODES] = partial[blockIdx.x] + sb[tid];
}

__global__ void k_scatter(const int* __restrict__ src, const int* __restrict__ dst,
                          int* __restrict__ cursor, int* __restrict__ csr_src) {
  int e = blockIdx.x * 256 + threadIdx.x;
  if (e < N_EDGES) {
    int d = dst[e];
    int pos = atomicAdd(&cursor[d], 1);
    csr_src[pos] = src[e];
  }
}

// ---------------- projection GEMM: C[M][64] = A[M][K] @ W[K][64] ----------
// 64-row x 64-col tile per block; k staged in 20-wide chunks (6 KB LDS ->
// high occupancy, coalesced staging). Each wave: 16 rows in registers, each
// W element reused 16x.

__global__ __launch_bounds__(256) void k_proj(const float* __restrict__ A,
                                              const float* __restrict__ W,
                                              float* __restrict__ C, int M, int K) {
  __shared__ float sA[64][24];  // 24-float row stride: 96 B, 16B-aligned
  int tid = threadIdx.x;
  int lane = tid & 63;
  int wv = tid >> 6;
  int row0 = blockIdx.x * 64;
  float acc[16];
#pragma unroll
  for (int r = 0; r < 16; r++) acc[r] = 0.f;

  for (int c = 0; c < K; c += PROJ_CHUNK) {
    __syncthreads();
    for (int idx = tid; idx < 64 * PROJ_CHUNK; idx += 256) {
      int r = idx / PROJ_CHUNK;
      int k = idx % PROJ_CHUNK;
      int row = row0 + r;
      sA[r][k] = (row < M) ? A[(size_t)row * K + c + k] : 0.f;
    }
    __syncthreads();
#pragma unroll
    for (int k4 = 0; k4 < PROJ_CHUNK / 4; k4++) {
      int k = c + k4 * 4;
      float w0 = W[(k + 0) * 64 + lane];
      float w1 = W[(k + 1) * 64 + lane];
      float w2 = W[(k + 2) * 64 + lane];
      float w3 = W[(k + 3) * 64 + lane];
#pragma unroll
      for (int r = 0; r < 16; r++) {
        const float4 f4 = *(const float4*)&sA[wv * 16 + r][k4 * 4];
        acc[r] += f4.x * w0 + f4.y * w1 + f4.z * w2 + f4.w * w3;
      }
    }
  }
#pragma unroll
  for (int r = 0; r < 16; r++) {
    int row = row0 + wv * 16 + r;
    if (row < M) C[(size_t)row * 64 + lane] = acc[r];
  }
}

// ---------------- gather + combine: hs = (proj_poi[pid] + proj_cat[cid]
//                                          + x[2:5] @ W_in[400:403]) * dinv ----

__global__ __launch_bounds__(256) void k_gather(
    const float* __restrict__ x, const float* __restrict__ proj_poi,
    const float* __restrict__ proj_cat, const float* __restrict__ W_in,
    const float* __restrict__ dinv, float* __restrict__ hs) {
  int lane = threadIdx.x & 63;
  int w = threadIdx.x >> 6;
  int node = blockIdx.x * 4 + w;
  int pid = (int)x[node * 5 + 0];
  int cid = (int)x[node * 5 + 1];
  float x2 = x[node * 5 + 2];
  float x3 = x[node * 5 + 3];
  float x4 = x[node * 5 + 4];
  float v = proj_poi[(size_t)pid * 64 + lane] + proj_cat[(size_t)cid * 64 + lane] +
            x2 * W_in[400 * 64 + lane] + x3 * W_in[401 * 64 + lane] +
            x4 * W_in[402 * 64 + lane];
  hs[(size_t)node * 64 + lane] = v * dinv[node];
}

// ---------------- middle transform: hs = (feat @ W) * dinv ----------------

__global__ __launch_bounds__(256) void k_xform(const float* __restrict__ feat,
                                               const float* __restrict__ W,
                                               const float* __restrict__ dinv,
                                               float* __restrict__ hs) {
  __shared__ float sW[64 * 64];
  int tid = threadIdx.x;
  int lane = tid & 63;
  int w = tid >> 6;
  for (int k = tid; k < 64 * 64; k += 256) sW[k] = W[k];
  __syncthreads();
  int node = blockIdx.x * 4 + w;
  float f = feat[(size_t)node * 64 + lane];
  float acc = 0.f;
#pragma unroll
  for (int k = 0; k < 64; k++) {
    float fk = __shfl(f, k, 64);
    acc += fk * sW[k * 64 + lane];
  }
  hs[(size_t)node * 64 + lane] = acc * dinv[node];
}

// ---------------- aggregation + epilogue ----------------
// t = dinv[i]*(sum_edges hs[src] + hs[i]) + b;  MODE 0: leaky(t)  MODE 1: leaky(t)+t
// 8 independent accumulators -> 8 outstanding LLC gathers per wave.

template <int MODE>
__global__ __launch_bounds__(256) void k_agg(const float* __restrict__ hs,
                                             const int* __restrict__ row_start,
                                             const int* __restrict__ csr_src,
                                             const float* __restrict__ dinv,
                                             const float* __restrict__ bias,
                                             float* __restrict__ out) {
  int lane = threadIdx.x & 63;
  int w = threadIdx.x >> 6;
  int node = blockIdx.x * 4 + w;
  int r0 = row_start[node];
  int r1 = row_start[node + 1];
  float a0 = 0.f, a1 = 0.f, a2 = 0.f, a3 = 0.f;
  float a4 = 0.f, a5 = 0.f, a6 = 0.f, a7 = 0.f;
  int e = r0;
  for (; e + 8 <= r1; e += 8) {
    int s0 = csr_src[e + 0];
    int s1 = csr_src[e + 1];
    int s2 = csr_src[e + 2];
    int s3 = csr_src[e + 3];
    int s4 = csr_src[e + 4];
    int s5 = csr_src[e + 5];
    int s6 = csr_src[e + 6];
    int s7 = csr_src[e + 7];
    a0 += hs[(size_t)s0 * 64 + lane];
    a1 += hs[(size_t)s1 * 64 + lane];
    a2 += hs[(size_t)s2 * 64 + lane];
    a3 += hs[(size_t)s3 * 64 + lane];
    a4 += hs[(size_t)s4 * 64 + lane];
    a5 += hs[(size_t)s5 * 64 + lane];
    a6 += hs[(size_t)s6 * 64 + lane];
    a7 += hs[(size_t)s7 * 64 + lane];
  }
  for (; e < r1; e++) a0 += hs[(size_t)csr_src[e] * 64 + lane];
  float acc = ((a0 + a1) + (a2 + a3)) + ((a4 + a5) + (a6 + a7));
  float t = dinv[node] * (acc + hs[(size_t)node * 64 + lane]) + bias[lane];
  float lt = (t >= 0.f) ? t : NEG_SLOPE * t;
  out[(size_t)node * 64 + lane] = MODE ? (lt + t) : lt;
}

// ---------------- output head (64 -> 1) ----------------

__global__ __launch_bounds__(256) void k_out_xform(const float* __restrict__ feat,
                                                   const float* __restrict__ W_out,
                                                   const float* __restrict__ dinv,
                                                   float* __restrict__ hs1) {
  int lane = threadIdx.x & 63;
  int w = threadIdx.x >> 6;
  int node = blockIdx.x * 4 + w;
  float v = feat[(size_t)node * 64 + lane] * W_out[lane];
#pragma unroll
  for (int off = 32; off; off >>= 1) v += __shfl_xor(v, off, 64);
  if (lane == 0) hs1[node] = v * dinv[node];
}

__global__ __launch_bounds__(256) void k_out_agg(const float* __restrict__ hs1,
                                                 const int* __restrict__ row_start,
                                                 const int* __restrict__ csr_src,
                                                 const float* __restrict__ dinv,
                                                 const float* __restrict__ b_out,
                                                 float* __restrict__ g) {
  int lane = threadIdx.x & 63;
  int w = threadIdx.x >> 6;
  int node = blockIdx.x * 4 + w;
  int r0 = row_start[node];
  int r1 = row_start[node + 1];
  float acc = 0.f;
  for (int e = r0 + lane; e < r1; e += 64) acc += hs1[csr_src[e]];
#pragma unroll
  for (int off = 32; off; off >>= 1) acc += __shfl_xor(acc, off, 64);
  if (lane == 0) {
    float t = dinv[node] * (acc + hs1[node]) + b_out[0];
    g[node] = (t >= 0.f) ? t : NEG_SLOPE * t;
  }
}

// ---------------- FC head ----------------

__global__ __launch_bounds__(128) void k_fc1(const float* __restrict__ g,
                                             const float* __restrict__ fc1_W,
                                             float* __restrict__ h128) {
  int j = threadIdx.x;  // 0..127
  int base = blockIdx.x * 128;
  int end = base + 128;
  if (end > N_NODES) end = N_NODES;
  float acc = 0.f;
  for (int i = base; i < end; i++) acc += g[i] * fc1_W[(size_t)i * 128 + j];
  atomicAdd(&h128[j], acc);
}

__global__ __launch_bounds__(256) void k_fc2(const float* __restrict__ h128raw,
                                             const float* __restrict__ fc1_b,
                                             const float* __restrict__ fc2_W,
                                             const float* __restrict__ fc2_b,
                                             float* __restrict__ out) {
  __shared__ float sh[128];
  int tid = threadIdx.x;
  if (tid < 128) {
    float v = h128raw[tid] + fc1_b[tid];
    sh[tid] = (v > 0.f) ? v : 0.f;
  }
  __syncthreads();
  int p = blockIdx.x * 256 + tid;
  if (p < POI_LEN) {
    float acc = fc2_b[p];
#pragma unroll 8
    for (int j = 0; j < 128; j++) acc += sh[j] * fc2_W[(size_t)j * POI_LEN + p];
    out[p] = (acc > 0.f) ? acc : 0.f;
  }
}

// ---------------- launch ----------------

extern "C" void kernel_launch(void* const* d_in, const int* in_sizes, int n_in,
                              void* d_out, int out_size, void* d_ws, size_t ws_size,
                              hipStream_t stream) {
  const float* x       = (const float*)d_in[0];
  const int*   ei      = (const int*)d_in[1];
  const float* poi_emb = (const float*)d_in[2];
  const float* cat_emb = (const float*)d_in[3];
  const float* W_in    = (const float*)d_in[4];
  const float* b_in    = (const float*)d_in[5];
  const float* gcn_Ws  = (const float*)d_in[6];
  const float* gcn_bs  = (const float*)d_in[7];
  const float* W_out   = (const float*)d_in[8];
  const float* b_out   = (const float*)d_in[9];
  const float* fc1_W   = (const float*)d_in[10];
  const float* fc1_b   = (const float*)d_in[11];
  const float* fc2_W   = (const float*)d_in[12];
  const float* fc2_b   = (const float*)d_in[13];
  const int* src = ei;
  const int* dst = ei + N_EDGES;

  char* p = (char*)d_ws;
  auto take = [&](size_t bytes) {
    char* r = p;
    p += (bytes + 255) & ~(size_t)255;
    return r;
  };
  int*   cnt       = (int*)take((size_t)N_NODES * 4);
  int*   cursor    = (int*)take((size_t)N_NODES * 4);
  int*   row_start = (int*)take((size_t)(N_NODES + 1) * 4);
  float* dinv      = (float*)take((size_t)N_NODES * 4);
  int*   csr_src   = (int*)take((size_t)N_EDGES * 4);
  float* feat      = (float*)take((size_t)N_NODES * 64 * 4);
  float* hs        = (float*)take((size_t)N_NODES * 64 * 4);
  float* proj_poi  = (float*)take((size_t)POI_LEN * 64 * 4);
  float* proj_cat  = (float*)take((size_t)CAT_LEN * 64 * 4);
  float* hs1       = (float*)take((size_t)N_NODES * 4);
  float* g         = (float*)take((size_t)N_NODES * 4);
  float* h128      = (float*)take(128 * 4);
  int*   partial   = (int*)take((size_t)N_CHUNKS * 4);
  float* out       = (float*)d_out;

  const int nb4 = N_NODES / 4;            // 9583
  const int nbE = (N_EDGES + 255) / 256;  // 4792

  k_zero<<<(N_NODES + 255) / 256, 256, 0, stream>>>(cnt, h128);
  k_count<<<nbE, 256, 0, stream>>>(dst, cnt);
  k_scan1<<<N_CHUNKS, 256, 0, stream>>>(cnt, partial, dinv);
  k_scan2<<<1, 256, 0, stream>>>(partial);
  k_scan3<<<N_CHUNKS, 256, 0, stream>>>(cnt, partial, row_start, cursor);
  k_scatter<<<nbE, 256, 0, stream>>>(src, dst, cursor, csr_src);

  // front-end: dense projections + cheap 256B-row gather
  k_proj<<<(POI_LEN + 63) / 64, 256, 0, stream>>>(poi_emb, W_in, proj_poi,
                                                  POI_LEN, POI_DIM);
  k_proj<<<(CAT_LEN + 63) / 64, 256, 0, stream>>>(cat_emb, W_in + 300 * 64,
                                                  proj_cat, CAT_LEN, CAT_DIM);
  k_gather<<<nb4, 256, 0, stream>>>(x, proj_poi, proj_cat, W_in, dinv, hs);
  k_agg<0><<<nb4, 256, 0, stream>>>(hs, row_start, csr_src, dinv, b_in, feat);

  for (int l = 0; l < 5; l++) {
    k_xform<<<nb4, 256, 0, stream>>>(feat, gcn_Ws + (size_t)l * 64 * 64, dinv, hs);
    k_agg<1><<<nb4, 256, 0, stream>>>(hs, row_start, csr_src, dinv,
                                      gcn_bs + (size_t)l * 64, feat);
  }

  k_out_xform<<<nb4, 256, 0, stream>>>(feat, W_out, dinv, hs1);
  k_out_agg<<<nb4, 256, 0, stream>>>(hs1, row_start, csr_src, dinv, b_out, g);
  k_fc1<<<(N_NODES + 127) / 128, 128, 0, stream>>>(g, fc1_W, h128);
  k_fc2<<<(POI_LEN + 255) / 256, 256, 0, stream>>>(h128, fc1_b, fc2_W, fc2_b, out);
}